// Round 12
// baseline (10443.331 us; speedup 1.0000x reference)
//
#include <hip/hip_runtime.h>
#include <cstdint>

typedef unsigned short u16;
typedef uint32_t u32;
typedef float f32x4 __attribute__((ext_vector_type(4)));
typedef __bf16 bf16x8 __attribute__((ext_vector_type(8)));

#define GLDS16(gp, lp)                                                                   \
  __builtin_amdgcn_global_load_lds((const __attribute__((address_space(1))) void*)(gp),  \
                                   (__attribute__((address_space(3))) void*)(lp), 16, 0, 0)

__device__ __forceinline__ float blo(u32 u) { return __uint_as_float(u << 16); }
__device__ __forceinline__ float bhi(u32 u) { return __uint_as_float(u & 0xFFFF0000u); }
__device__ __forceinline__ u16 f2b(float f) {
  u32 u = __float_as_uint(f);
  u32 r = u + 0x7FFFu + ((u >> 16) & 1u);
  return (u16)(r >> 16);
}

// ---------------------------------------------------------------------------
// f32 -> bf16 conversion (rte), 8 elements per thread, grid-stride.
// ---------------------------------------------------------------------------
__global__ __launch_bounds__(256) void ctil_cvt_f2b(
    const float* __restrict__ in, u16* __restrict__ out, long n)
{
  long i = ((long)blockIdx.x * blockDim.x + threadIdx.x) * 8;
  const long stride = (long)gridDim.x * blockDim.x * 8;
  for (; i < n; i += stride) {
    float4 a = *reinterpret_cast<const float4*>(in + i);
    float4 b = *reinterpret_cast<const float4*>(in + i + 4);
    uint4 o;
    o.x = (u32)f2b(a.x) | ((u32)f2b(a.y) << 16);
    o.y = (u32)f2b(a.z) | ((u32)f2b(a.w) << 16);
    o.z = (u32)f2b(b.x) | ((u32)f2b(b.y) << 16);
    o.w = (u32)f2b(b.z) | ((u32)f2b(b.w) << 16);
    *reinterpret_cast<uint4*>(out + i) = o;
  }
}

// ---------------------------------------------------------------------------
// 256x256 GEMM, BK=32, 2 blocks/CU: C = A @ W^T, bf16, f32 acc.
// 8 waves (2M x 4N), per-wave 128x64. LDS 2x(A 256x32 + B 256x32) = 64 KiB
// -> 2 blocks/CU (4 waves/SIMD): cross-block TLP absorbs barrier drains.
// Swizzle (64B rows): phys_slot = slot ^ ((row>>1)&3) -> 2-way bank alias
// (free). Staging: linear LDS dest, inverse-swizzled global source
// (sq = (l&3)^((l>>3)&3)). Fence-light r7 schedule halved: counted vmcnt(2)
// publishes at P3/P7, lgkm0 WAR guards at P2/P6, 1 barrier/phase.
// z: 0=K,1=V (lda/ldc=2048), 2..9=Q_t, 10..17=G_t (lda/ldc=16384).
// ---------------------------------------------------------------------------
__global__ __launch_bounds__(512, 4) void ctil_gemm256(
    const u16* __restrict__ Hb, const u16* __restrict__ Wqb,
    const u16* __restrict__ Wkb, const u16* __restrict__ Wvb,
    const u16* __restrict__ Wgb,
    u16* __restrict__ Kb, u16* __restrict__ Vb,
    u16* __restrict__ Qb, u16* __restrict__ Gb,
    int zbase)
{
  const int z = blockIdx.z + zbase;
  const u16* A;
  const u16* W;
  u16* C;
  int lda, ldc;
  if (z < 2) {
    A = Hb; lda = 2048; ldc = 2048;
    W = (z == 0) ? Wkb : Wvb;
    C = (z == 0) ? Kb : Vb;
  } else {
    const int t = (z - 2) & 7;
    A = Hb + t * 2048; lda = 16384; ldc = 16384;
    W = ((z < 10) ? Wqb : Wgb) + (size_t)t * (size_t)(2048 * 2048);
    C = ((z < 10) ? Qb : Gb) + t * 2048;
  }
  const int bm = blockIdx.x, bn = blockIdx.y;

  const int tid = (int)threadIdx.x;
  const int lane = tid & 63, wid = tid >> 6;
  const int wm = wid >> 2, wn = wid & 3;   // 2 x 4 wave grid

  __shared__ __align__(16) u16 As[2][8192];   // [buf][row*32 + k], 16 KiB ea
  __shared__ __align__(16) u16 Bs[2][8192];

  // staging: wave wid covers rows wid*32..wid*32+31; issue j covers 16 rows
  // wid*32 + j*16 + (lane>>2). Physical kslot lane&3 holds logical kslot
  // (lane&3)^((lane>>3)&3)  (inverse of the read swizzle).
  const int srl = lane >> 2;                 // row within 16-row issue
  const int sq  = (lane & 3) ^ ((lane >> 3) & 3);
  const u16* Ag = A + (size_t)(bm * 256 + wid * 32 + srl) * lda + sq * 8;
  const u16* Bg = W + (size_t)(bn * 256 + wid * 32 + srl) * 2048 + sq * 8;

#define STAGE(buf, kt, j)                                                     \
  do {                                                                        \
    GLDS16(Ag + (size_t)((j) * 16) * lda + (kt) * 32,                         \
           &As[buf][((j) * 16 + wid * 32) * 32]);                             \
    GLDS16(Bg + (size_t)((j) * 16) * 2048 + (kt) * 32,                        \
           &Bs[buf][((j) * 16 + wid * 32) * 32]);                             \
  } while (0)

  // fragment reads (swizzled): logical kslot g (=lane>>4) of row r lives at
  // u16 index r*32 + (g ^ ((r>>1)&3))*8.
  const int la = lane & 15, g = lane >> 4;
  const int rsw = (la >> 1) & 3;             // (row>>1)&3 for all frag rows
  const int arow = wm * 128 + la;            // + mh*64 + j*16
  const int brow = wn * 64 + la;             // + nh*32 + j*16
  const int sl0 = ((g ^ rsw) << 3);

  bf16x8 aR[4];          // A frags: current mh half
  bf16x8 bR[2][2];       // B frags: both halves live, [nh][jj]
  f32x4 acc[8][4] = {};

#define DSA(buf, mh)                                                          \
  do {                                                                        \
    _Pragma("unroll") for (int j = 0; j < 4; ++j) {                           \
      const int r_ = (arow + (mh) * 64 + j * 16) * 32;                        \
      aR[j] = *reinterpret_cast<const bf16x8*>(&As[buf][r_ + sl0]);           \
    }                                                                         \
  } while (0)

#define DSB(buf, nh)                                                          \
  do {                                                                        \
    _Pragma("unroll") for (int j = 0; j < 2; ++j) {                           \
      const int r_ = (brow + (nh) * 32 + j * 16) * 32;                        \
      bR[nh][j] = *reinterpret_cast<const bf16x8*>(&Bs[buf][r_ + sl0]);       \
    }                                                                         \
  } while (0)

#define MFMA8(mh, nh)                                                         \
  do {                                                                        \
    _Pragma("unroll") for (int j = 0; j < 4; ++j)                             \
    _Pragma("unroll") for (int jj = 0; jj < 2; ++jj)                          \
      acc[(mh) * 4 + j][(nh) * 2 + jj] =                                      \
          __builtin_amdgcn_mfma_f32_16x16x32_bf16(                            \
              aR[j], bR[nh][jj], acc[(mh) * 4 + j][(nh) * 2 + jj],            \
              0, 0, 0);                                                       \
  } while (0)

#define BAR()                                                                 \
  do {                                                                        \
    __builtin_amdgcn_s_barrier();                                             \
    asm volatile("" ::: "memory");                                            \
  } while (0)
#define LGKMW() asm volatile("s_waitcnt lgkmcnt(0)" ::: "memory")
#define VMW(n) asm volatile("s_waitcnt vmcnt(" #n ")" ::: "memory")
#define PRIO_ON()  __builtin_amdgcn_s_setprio(1)
#define PRIO_OFF() __builtin_amdgcn_s_setprio(0)

  // prologue: buf0 <- tile0 (2 STAGE = 4 loads); buf1 <- tile1 j0 (2 loads);
  // publish buf0: vmcnt(2) + BAR.
  STAGE(0, 0, 0);
  STAGE(0, 0, 1);
  STAGE(1, 1, 0);
  VMW(2);
  BAR();

#pragma unroll 1
  for (int it = 0; it < 32; ++it) {
    const int k1 = 2 * it + 1, k2 = 2 * it + 2, k3 = 2 * it + 3;
    const bool nl = (it < 31);
    // ---- P0: reads of buf0 quadrant (0,0); finish buf1(k1) staging.
    DSA(0, 0); DSB(0, 0);
    STAGE(1, k1, 1);
    PRIO_ON(); MFMA8(0, 0); PRIO_OFF();
    BAR();
    // ---- P1
    DSB(0, 1);
    PRIO_ON(); MFMA8(0, 1); PRIO_OFF();
    BAR();
    // ---- P2 (last buf0 reads; WAR guard before buf0 overwrite at P3)
    DSA(0, 1);
    PRIO_ON(); MFMA8(1, 1); PRIO_OFF();
    LGKMW();
    BAR();
    // ---- P3: stage buf0(k2) j0; publish buf1(k1): vmcnt(2)+BAR.
    if (nl) STAGE(0, k2, 0);
    PRIO_ON(); MFMA8(1, 0); PRIO_OFF();
    if (nl) VMW(2); else VMW(0);
    BAR();
    // ---- P4: reads of buf1 quadrant (0,0); finish buf0(k2) staging.
    DSA(1, 0); DSB(1, 0);
    if (nl) STAGE(0, k2, 1);
    PRIO_ON(); MFMA8(0, 0); PRIO_OFF();
    BAR();
    // ---- P5
    DSB(1, 1);
    PRIO_ON(); MFMA8(0, 1); PRIO_OFF();
    BAR();
    // ---- P6 (last buf1 reads; WAR guard before buf1 overwrite at P7)
    DSA(1, 1);
    PRIO_ON(); MFMA8(1, 1); PRIO_OFF();
    LGKMW();
    BAR();
    // ---- P7: stage buf1(k3) j0; publish buf0(k2): vmcnt(2)+BAR.
    if (nl) STAGE(1, k3, 0);
    PRIO_ON(); MFMA8(1, 0); PRIO_OFF();
    if (nl) VMW(2); else VMW(0);
    BAR();
  }

  // ---- epilogue: C write (C/D layout: col=lane&15, row=(lane>>4)*4+r)
  const int cl = lane & 15, cq = lane >> 4;
#pragma unroll
  for (int mf = 0; mf < 8; ++mf) {
#pragma unroll
    for (int r = 0; r < 4; ++r) {
      const int row = bm * 256 + wm * 128 + mf * 16 + cq * 4 + r;
      u16* Cr = C + (size_t)row * ldc + bn * 256 + wn * 64 + cl;
#pragma unroll
      for (int nf = 0; nf < 4; ++nf)
        Cr[nf * 16] = f2b(acc[mf][nf][r]);
    }
  }
#undef STAGE
#undef DSA
#undef DSB
#undef MFMA8
#undef BAR
#undef LGKMW
#undef VMW
}

// ---------------------------------------------------------------------------
// Fused epilogue: per batch b (one 256-thread block):
//   scores = Q K^T / sqrt(D) -> softmax -> ctx = attn V
//   g = sigmoid(Gpre + bg); x = H + g*ctx; out = LayerNorm(x)*gamma + beta
// Each thread owns an 8-wide contiguous e-slice (e0 = tid*8).
// Hb/K/V/Q/G are bf16; bg/gamma/beta are f32; Out is f32.
// ---------------------------------------------------------------------------
__global__ __launch_bounds__(256) void ctil_epilogue(
    const u16* __restrict__ Hb, const u16* __restrict__ Kb,
    const u16* __restrict__ Vb, const u16* __restrict__ Qb,
    const u16* __restrict__ Gb, const float* __restrict__ bgp,
    const float* __restrict__ gap, const float* __restrict__ bep,
    float* __restrict__ Out)
{
  const int b = blockIdx.x;
  const int tid = (int)threadIdx.x;
  const int lane = tid & 63, wid = tid >> 6;
  const size_t rbase = (size_t)b * 16384;
  const int e0 = tid * 8;

  __shared__ float red[256];
  __shared__ float r1s[4], r2s[4];

  u32 qw[8][4], kw[8][4];
#pragma unroll
  for (int t = 0; t < 8; ++t) {
    uint4 v = *reinterpret_cast<const uint4*>(Qb + rbase + t * 2048 + e0);
    qw[t][0] = v.x; qw[t][1] = v.y; qw[t][2] = v.z; qw[t][3] = v.w;
    uint4 w = *reinterpret_cast<const uint4*>(Kb + rbase + t * 2048 + e0);
    kw[t][0] = w.x; kw[t][1] = w.y; kw[t][2] = w.z; kw[t][3] = w.w;
  }

  float sc[64];
#pragma unroll
  for (int p = 0; p < 64; ++p) sc[p] = 0.f;

#pragma unroll
  for (int c = 0; c < 4; ++c) {
    float ql[8], qh[8], kl[8], kh[8];
#pragma unroll
    for (int t = 0; t < 8; ++t) {
      ql[t] = blo(qw[t][c]); qh[t] = bhi(qw[t][c]);
      kl[t] = blo(kw[t][c]); kh[t] = bhi(kw[t][c]);
    }
#pragma unroll
    for (int t = 0; t < 8; ++t)
#pragma unroll
      for (int s = 0; s < 8; ++s)
        sc[t * 8 + s] += ql[t] * kl[s] + qh[t] * kh[s];
  }

#pragma unroll
  for (int p = 0; p < 64; ++p) {
    float v = sc[p];
#pragma unroll
    for (int m = 1; m < 64; m <<= 1) v += __shfl_xor(v, m, 64);
    sc[p] = v;
  }
  if (lane == 0) {
#pragma unroll
    for (int p = 0; p < 64; ++p) red[wid * 64 + p] = sc[p];
  }
  __syncthreads();

  const float INVS = 0.022097086912079608f;  // 1/sqrt(2048)
#pragma unroll
  for (int p = 0; p < 64; ++p)
    sc[p] = (red[p] + red[64 + p] + red[128 + p] + red[192 + p]) * INVS;

#pragma unroll
  for (int t = 0; t < 8; ++t) {
    float m = sc[t * 8];
#pragma unroll
    for (int s = 1; s < 8; ++s) m = fmaxf(m, sc[t * 8 + s]);
    float l = 0.f;
#pragma unroll
    for (int s = 0; s < 8; ++s) {
      float e = __expf(sc[t * 8 + s] - m);
      sc[t * 8 + s] = e;
      l += e;
    }
    float inv = 1.f / l;
#pragma unroll
    for (int s = 0; s < 8; ++s) sc[t * 8 + s] *= inv;
  }

  u32 vw[8][4];
#pragma unroll
  for (int s = 0; s < 8; ++s) {
    uint4 v = *reinterpret_cast<const uint4*>(Vb + rbase + s * 2048 + e0);
    vw[s][0] = v.x; vw[s][1] = v.y; vw[s][2] = v.z; vw[s][3] = v.w;
  }

  for (int t = 0; t < 8; ++t) {
    float cx[8];
#pragma unroll
    for (int j = 0; j < 8; ++j) cx[j] = 0.f;
#pragma unroll
    for (int s = 0; s < 8; ++s) {
      float a = sc[t * 8 + s];
#pragma unroll
      for (int c = 0; c < 4; ++c) {
        cx[2 * c]     += a * blo(vw[s][c]);
        cx[2 * c + 1] += a * bhi(vw[s][c]);
      }
    }
    uint4 gu = *reinterpret_cast<const uint4*>(Gb + rbase + t * 2048 + e0);
    uint4 hu = *reinterpret_cast<const uint4*>(Hb + rbase + t * 2048 + e0);
    u32 ga[4] = {gu.x, gu.y, gu.z, gu.w};
    u32 ha[4] = {hu.x, hu.y, hu.z, hu.w};
    float bgv[8];
    *reinterpret_cast<float4*>(&bgv[0]) = *reinterpret_cast<const float4*>(bgp + t * 2048 + e0);
    *reinterpret_cast<float4*>(&bgv[4]) = *reinterpret_cast<const float4*>(bgp + t * 2048 + e0 + 4);
    float x[8];
    float s1 = 0.f, s2 = 0.f;
#pragma unroll
    for (int c = 0; c < 4; ++c) {
      float gl = blo(ga[c]) + bgv[2 * c];
      float gh = bhi(ga[c]) + bgv[2 * c + 1];
      float sgl = 1.f / (1.f + __expf(-gl));
      float sgh = 1.f / (1.f + __expf(-gh));
      float xl = blo(ha[c]) + sgl * cx[2 * c];
      float xh = bhi(ha[c]) + sgh * cx[2 * c + 1];
      x[2 * c] = xl; x[2 * c + 1] = xh;
      s1 += xl + xh;
      s2 += xl * xl + xh * xh;
    }
#pragma unroll
    for (int m = 1; m < 64; m <<= 1) {
      s1 += __shfl_xor(s1, m, 64);
      s2 += __shfl_xor(s2, m, 64);
    }
    if (lane == 0) { r1s[wid] = s1; r2s[wid] = s2; }
    __syncthreads();
    const float invD = 1.f / 2048.f;
    float S1 = r1s[0] + r1s[1] + r1s[2] + r1s[3];
    float S2 = r2s[0] + r2s[1] + r2s[2] + r2s[3];
    float mu = S1 * invD;
    float var = S2 * invD - mu * mu;
    float rstd = rsqrtf(var + 1e-5f);
    float gmv[8], btv[8];
    *reinterpret_cast<float4*>(&gmv[0]) = *reinterpret_cast<const float4*>(gap + t * 2048 + e0);
    *reinterpret_cast<float4*>(&gmv[4]) = *reinterpret_cast<const float4*>(gap + t * 2048 + e0 + 4);
    *reinterpret_cast<float4*>(&btv[0]) = *reinterpret_cast<const float4*>(bep + t * 2048 + e0);
    *reinterpret_cast<float4*>(&btv[4]) = *reinterpret_cast<const float4*>(bep + t * 2048 + e0 + 4);
    float4 o1, o2;
    o1.x = (x[0] - mu) * rstd * gmv[0] + btv[0];
    o1.y = (x[1] - mu) * rstd * gmv[1] + btv[1];
    o1.z = (x[2] - mu) * rstd * gmv[2] + btv[2];
    o1.w = (x[3] - mu) * rstd * gmv[3] + btv[3];
    o2.x = (x[4] - mu) * rstd * gmv[4] + btv[4];
    o2.y = (x[5] - mu) * rstd * gmv[5] + btv[5];
    o2.z = (x[6] - mu) * rstd * gmv[6] + btv[6];
    o2.w = (x[7] - mu) * rstd * gmv[7] + btv[7];
    *reinterpret_cast<float4*>(Out + rbase + t * 2048 + e0) = o1;
    *reinterpret_cast<float4*>(Out + rbase + t * 2048 + e0 + 4) = o2;
    __syncthreads();
  }
}

// ---------------------------------------------------------------------------
extern "C" void kernel_launch(void* const* d_in, const int* in_sizes, int n_in,
                              void* d_out, int out_size, void* d_ws, size_t ws_size,
                              hipStream_t stream)
{
  const float* H  = (const float*)d_in[0];
  const float* Wq = (const float*)d_in[1];
  const float* Wk = (const float*)d_in[2];
  const float* Wv = (const float*)d_in[3];
  const float* Wg = (const float*)d_in[4];
  const float* bg = (const float*)d_in[5];
  const float* ga = (const float*)d_in[6];
  const float* be = (const float*)d_in[7];
  float* Out = (float*)d_out;

  const size_t NWQ = 33554432, NWK = 4194304;
  // ws layout (u16 elems): Wqb | Wgb | Wkb | Wvb | per-chunk {Hb, K, V, G, Q}
  u16* Wqb = (u16*)d_ws;
  u16* Wgb = Wqb + NWQ;
  u16* Wkb = Wgb + NWQ;
  u16* Wvb = Wkb + NWK;
  u16* chunkbase = Wvb + NWK;  // 150,994,944 bytes

  // chunk over batches: per batch needs 5 * 16384 * 2 = 163840 bytes.
  // CB must stay >= 256 (Q/G GEMM uses 256-row tiles) -> nch <= 16.
  const size_t fixed = 150994944ull;
  int nch = 1;
  while (nch < 16 && fixed + (size_t)(4096 / nch) * 163840ull > ws_size) nch <<= 1;
  const int CB = 4096 / nch;

  u16* Hb = chunkbase;
  u16* Kw = Hb + (size_t)CB * 16384;
  u16* Vw = Kw + (size_t)CB * 16384;
  u16* Gw = Vw + (size_t)CB * 16384;
  u16* Qw = Gw + (size_t)CB * 16384;

  // convert weights once per call
  ctil_cvt_f2b<<<2048, 256, 0, stream>>>(Wq, Wqb, (long)NWQ);
  ctil_cvt_f2b<<<2048, 256, 0, stream>>>(Wg, Wgb, (long)NWQ);
  ctil_cvt_f2b<<<512, 256, 0, stream>>>(Wk, Wkb, (long)NWK);
  ctil_cvt_f2b<<<512, 256, 0, stream>>>(Wv, Wvb, (long)NWK);

  for (int c = 0; c < nch; ++c) {
    const size_t off = (size_t)c * (size_t)CB * 16384;
    // convert H chunk
    ctil_cvt_f2b<<<2048, 256, 0, stream>>>(H + off, Hb, (long)CB * 16384);
    // K, V: M = CB*8 rows -> CB/32 m-tiles of 256
    ctil_gemm256<<<dim3(CB / 32, 8, 2), 512, 0, stream>>>(
        Hb, Wqb, Wkb, Wvb, Wgb, Kw, Vw, Qw, Gw, 0);
    // Q_t, Gpre_t: M = CB rows -> CB/256 m-tiles, 16 slices
    ctil_gemm256<<<dim3(CB / 256, 8, 16), 512, 0, stream>>>(
        Hb, Wqb, Wkb, Wvb, Wgb, Kw, Vw, Qw, Gw, 2);
    // fused attention + gate + residual + LN
    ctil_epilogue<<<dim3(CB), 256, 0, stream>>>(
        Hb, Kw, Vw, Qw, Gw, bg, ga, be, Out + off);
  }
}

// Round 13
// 1697.180 us; speedup vs baseline: 6.1533x; 6.1533x over previous
//
#include <hip/hip_runtime.h>
#include <cstdint>

typedef unsigned short u16;
typedef uint32_t u32;
typedef float f32x4 __attribute__((ext_vector_type(4)));
typedef __bf16 bf16x8 __attribute__((ext_vector_type(8)));

#define GLDS16(gp, lp)                                                                   \
  __builtin_amdgcn_global_load_lds((const __attribute__((address_space(1))) void*)(gp),  \
                                   (__attribute__((address_space(3))) void*)(lp), 16, 0, 0)

__device__ __forceinline__ float blo(u32 u) { return __uint_as_float(u << 16); }
__device__ __forceinline__ float bhi(u32 u) { return __uint_as_float(u & 0xFFFF0000u); }
__device__ __forceinline__ u16 f2b(float f) {
  u32 u = __float_as_uint(f);
  u32 r = u + 0x7FFFu + ((u >> 16) & 1u);
  return (u16)(r >> 16);
}

// ---------------------------------------------------------------------------
// f32 -> bf16 conversion (rte), 8 elements per thread, grid-stride.
// ---------------------------------------------------------------------------
__global__ __launch_bounds__(256) void ctil_cvt_f2b(
    const float* __restrict__ in, u16* __restrict__ out, long n)
{
  long i = ((long)blockIdx.x * blockDim.x + threadIdx.x) * 8;
  const long stride = (long)gridDim.x * blockDim.x * 8;
  for (; i < n; i += stride) {
    float4 a = *reinterpret_cast<const float4*>(in + i);
    float4 b = *reinterpret_cast<const float4*>(in + i + 4);
    uint4 o;
    o.x = (u32)f2b(a.x) | ((u32)f2b(a.y) << 16);
    o.y = (u32)f2b(a.z) | ((u32)f2b(a.w) << 16);
    o.z = (u32)f2b(b.x) | ((u32)f2b(b.y) << 16);
    o.w = (u32)f2b(b.z) | ((u32)f2b(b.w) << 16);
    *reinterpret_cast<uint4*>(out + i) = o;
  }
}

// ---------------------------------------------------------------------------
// 128x256 GEMM, BK=32, 2 blocks/CU TLP: C = A @ W^T, bf16, f32 acc.
// 8 waves (2M x 4N), per-wave 64x64 -> acc = 64 VGPR; total ~116 <= 128 cap
// (__launch_bounds__(512,4)). LDS 2x(A 128x32 + B 256x32) = 48 KiB ->
// 2 blocks/CU (4 waves/SIMD): co-resident block covers vmcnt drains.
// Swizzle (64B rows, HW-verified in r12): phys_slot = slot ^ ((row>>1)&3);
// staging = linear LDS dest + inverse-swizzled global source
// (sq = (l&3)^((l>>3)&3)). 4 phases per 2 K-steps:
//  PA: read buf0 A+B01 | stage tile k1 -> buf1 (3) | MFMA h0 | BAR
//  PB: read buf0 B23 | MFMA h1 | LGKMW(WAR) | VMW(0) publish buf1 | BAR
//  PC: read buf1 A+B01 | stage k2 -> buf0 | MFMA h0 | BAR
//  PD: read buf1 B23 | MFMA h1 | LGKMW | VMW(0) publish buf0 | BAR
// z: 0=K,1=V (lda/ldc=2048), 2..9=Q_t, 10..17=G_t (lda/ldc=16384).
// ---------------------------------------------------------------------------
__global__ __launch_bounds__(512, 4) void ctil_gemm128(
    const u16* __restrict__ Hb, const u16* __restrict__ Wqb,
    const u16* __restrict__ Wkb, const u16* __restrict__ Wvb,
    const u16* __restrict__ Wgb,
    u16* __restrict__ Kb, u16* __restrict__ Vb,
    u16* __restrict__ Qb, u16* __restrict__ Gb,
    int zbase)
{
  const int z = blockIdx.z + zbase;
  const u16* A;
  const u16* W;
  u16* C;
  int lda, ldc;
  if (z < 2) {
    A = Hb; lda = 2048; ldc = 2048;
    W = (z == 0) ? Wkb : Wvb;
    C = (z == 0) ? Kb : Vb;
  } else {
    const int t = (z - 2) & 7;
    A = Hb + t * 2048; lda = 16384; ldc = 16384;
    W = ((z < 10) ? Wqb : Wgb) + (size_t)t * (size_t)(2048 * 2048);
    C = ((z < 10) ? Qb : Gb) + t * 2048;
  }
  const int bm = blockIdx.x, bn = blockIdx.y;

  const int tid = (int)threadIdx.x;
  const int lane = tid & 63, wid = tid >> 6;
  const int wm = wid >> 2, wn = wid & 3;   // 2 x 4 wave grid, 64x64 each

  __shared__ __align__(16) u16 As[2][4096];   // [buf][row*32 + k], 128 rows
  __shared__ __align__(16) u16 Bs[2][8192];   // [buf][row*32 + k], 256 rows

  // staging: A: wave wid covers rows [wid*16, wid*16+16), 1 issue.
  //          B: wave wid covers rows [wid*32, wid*32+32), 2 issues of 16.
  // lane l -> row base + (l>>2), phys kslot l&3 holds logical kslot
  // (l&3)^((l>>3)&3) (inverse of read swizzle; 16-row bases are 0 mod 8).
  const int srl = lane >> 2;
  const int sq  = (lane & 3) ^ ((lane >> 3) & 3);
  const u16* Ag = A + (size_t)(bm * 128 + wid * 16 + srl) * lda + sq * 8;
  const u16* Bg = W + (size_t)(bn * 256 + wid * 32 + srl) * 2048 + sq * 8;

#define STAGE_A(buf, kt)                                                      \
  GLDS16(Ag + (size_t)(kt) * 32, &As[buf][(wid * 16) * 32])
#define STAGE_B(buf, kt, j)                                                   \
  GLDS16(Bg + (size_t)((j) * 16) * 2048 + (size_t)(kt) * 32,                  \
         &Bs[buf][(wid * 32 + (j) * 16) * 32])
#define STAGE3(buf, kt)                                                       \
  do { STAGE_A(buf, kt); STAGE_B(buf, kt, 0); STAGE_B(buf, kt, 1); } while (0)

  // fragment reads (swizzled): logical kslot g (=lane>>4) of row r lives at
  // u16 index r*32 + (g ^ ((r>>1)&3))*8; frag rows are la + 16j (16-aligned
  // offsets), so (r>>1)&3 = (la>>1)&3 for all frags.
  const int la = lane & 15, g = lane >> 4;
  const int rsw = (la >> 1) & 3;
  const int arow = wm * 64 + la;
  const int brow = wn * 64 + la;
  const int sl0 = ((g ^ rsw) << 3);

  bf16x8 aR[4];          // A frags (4 x 16 rows)
  bf16x8 bA[2], bB[2];   // B frags: cols 0-31 / 32-63
  f32x4 acc[4][4] = {};

#define DSA(buf)                                                              \
  do {                                                                        \
    _Pragma("unroll") for (int j = 0; j < 4; ++j)                             \
      aR[j] = *reinterpret_cast<const bf16x8*>(                               \
          &As[buf][(arow + j * 16) * 32 + sl0]);                              \
  } while (0)

#define DSB0(buf)                                                             \
  do {                                                                        \
    bA[0] = *reinterpret_cast<const bf16x8*>(&Bs[buf][(brow) * 32 + sl0]);    \
    bA[1] = *reinterpret_cast<const bf16x8*>(&Bs[buf][(brow + 16) * 32 + sl0]); \
  } while (0)

#define DSB1(buf)                                                             \
  do {                                                                        \
    bB[0] = *reinterpret_cast<const bf16x8*>(&Bs[buf][(brow + 32) * 32 + sl0]); \
    bB[1] = *reinterpret_cast<const bf16x8*>(&Bs[buf][(brow + 48) * 32 + sl0]); \
  } while (0)

#define MFMA_H0()                                                             \
  do {                                                                        \
    _Pragma("unroll") for (int j = 0; j < 4; ++j) {                           \
      acc[j][0] = __builtin_amdgcn_mfma_f32_16x16x32_bf16(aR[j], bA[0],       \
                                                          acc[j][0], 0, 0, 0);\
      acc[j][1] = __builtin_amdgcn_mfma_f32_16x16x32_bf16(aR[j], bA[1],       \
                                                          acc[j][1], 0, 0, 0);\
    }                                                                         \
  } while (0)

#define MFMA_H1()                                                             \
  do {                                                                        \
    _Pragma("unroll") for (int j = 0; j < 4; ++j) {                           \
      acc[j][2] = __builtin_amdgcn_mfma_f32_16x16x32_bf16(aR[j], bB[0],       \
                                                          acc[j][2], 0, 0, 0);\
      acc[j][3] = __builtin_amdgcn_mfma_f32_16x16x32_bf16(aR[j], bB[1],       \
                                                          acc[j][3], 0, 0, 0);\
    }                                                                         \
  } while (0)

#define BAR()                                                                 \
  do {                                                                        \
    __builtin_amdgcn_s_barrier();                                             \
    asm volatile("" ::: "memory");                                            \
  } while (0)
#define LGKMW() asm volatile("s_waitcnt lgkmcnt(0)" ::: "memory")
#define VMW0() asm volatile("s_waitcnt vmcnt(0)" ::: "memory")
#define PRIO_ON()  __builtin_amdgcn_s_setprio(1)
#define PRIO_OFF() __builtin_amdgcn_s_setprio(0)

  // prologue: stage tile0 -> buf0; drain; publish.
  STAGE3(0, 0);
  VMW0();
  BAR();

#pragma unroll 1
  for (int j = 0; j < 32; ++j) {
    const int k1 = 2 * j + 1, k2 = 2 * j + 2;
    const bool nl = (j < 31);
    // ---- PA: compute buf0 half0; stage k1 -> buf1.
    DSA(0); DSB0(0);
    STAGE3(1, k1);
    PRIO_ON(); MFMA_H0(); PRIO_OFF();
    BAR();
    // ---- PB: compute buf0 half1; WAR-drain buf0 reads; publish buf1(k1).
    DSB1(0);
    PRIO_ON(); MFMA_H1(); PRIO_OFF();
    LGKMW();
    VMW0();
    BAR();
    // ---- PC: compute buf1 half0; stage k2 -> buf0 (freed at PB).
    DSA(1); DSB0(1);
    if (nl) STAGE3(0, k2);
    PRIO_ON(); MFMA_H0(); PRIO_OFF();
    BAR();
    // ---- PD: compute buf1 half1; WAR-drain; publish buf0(k2).
    DSB1(1);
    PRIO_ON(); MFMA_H1(); PRIO_OFF();
    LGKMW();
    if (nl) VMW0();
    BAR();
  }

  // ---- epilogue: C write (C/D layout: col=lane&15, row=(lane>>4)*4+r)
  const int cl = lane & 15, cq = lane >> 4;
#pragma unroll
  for (int mf = 0; mf < 4; ++mf) {
#pragma unroll
    for (int r = 0; r < 4; ++r) {
      const int row = bm * 128 + wm * 64 + mf * 16 + cq * 4 + r;
      u16* Cr = C + (size_t)row * ldc + bn * 256 + wn * 64 + cl;
#pragma unroll
      for (int nf = 0; nf < 4; ++nf)
        Cr[nf * 16] = f2b(acc[mf][nf][r]);
    }
  }
#undef STAGE_A
#undef STAGE_B
#undef STAGE3
#undef DSA
#undef DSB0
#undef DSB1
#undef MFMA_H0
#undef MFMA_H1
#undef BAR
#undef LGKMW
#undef VMW0
}

// ---------------------------------------------------------------------------
// Fused epilogue: per batch b (one 256-thread block):
//   scores = Q K^T / sqrt(D) -> softmax -> ctx = attn V
//   g = sigmoid(Gpre + bg); x = H + g*ctx; out = LayerNorm(x)*gamma + beta
// Each thread owns an 8-wide contiguous e-slice (e0 = tid*8).
// Hb/K/V/Q/G are bf16; bg/gamma/beta are f32; Out is f32.
// ---------------------------------------------------------------------------
__global__ __launch_bounds__(256) void ctil_epilogue(
    const u16* __restrict__ Hb, const u16* __restrict__ Kb,
    const u16* __restrict__ Vb, const u16* __restrict__ Qb,
    const u16* __restrict__ Gb, const float* __restrict__ bgp,
    const float* __restrict__ gap, const float* __restrict__ bep,
    float* __restrict__ Out)
{
  const int b = blockIdx.x;
  const int tid = (int)threadIdx.x;
  const int lane = tid & 63, wid = tid >> 6;
  const size_t rbase = (size_t)b * 16384;
  const int e0 = tid * 8;

  __shared__ float red[256];
  __shared__ float r1s[4], r2s[4];

  u32 qw[8][4], kw[8][4];
#pragma unroll
  for (int t = 0; t < 8; ++t) {
    uint4 v = *reinterpret_cast<const uint4*>(Qb + rbase + t * 2048 + e0);
    qw[t][0] = v.x; qw[t][1] = v.y; qw[t][2] = v.z; qw[t][3] = v.w;
    uint4 w = *reinterpret_cast<const uint4*>(Kb + rbase + t * 2048 + e0);
    kw[t][0] = w.x; kw[t][1] = w.y; kw[t][2] = w.z; kw[t][3] = w.w;
  }

  float sc[64];
#pragma unroll
  for (int p = 0; p < 64; ++p) sc[p] = 0.f;

#pragma unroll
  for (int c = 0; c < 4; ++c) {
    float ql[8], qh[8], kl[8], kh[8];
#pragma unroll
    for (int t = 0; t < 8; ++t) {
      ql[t] = blo(qw[t][c]); qh[t] = bhi(qw[t][c]);
      kl[t] = blo(kw[t][c]); kh[t] = bhi(kw[t][c]);
    }
#pragma unroll
    for (int t = 0; t < 8; ++t)
#pragma unroll
      for (int s = 0; s < 8; ++s)
        sc[t * 8 + s] += ql[t] * kl[s] + qh[t] * kh[s];
  }

#pragma unroll
  for (int p = 0; p < 64; ++p) {
    float v = sc[p];
#pragma unroll
    for (int m = 1; m < 64; m <<= 1) v += __shfl_xor(v, m, 64);
    sc[p] = v;
  }
  if (lane == 0) {
#pragma unroll
    for (int p = 0; p < 64; ++p) red[wid * 64 + p] = sc[p];
  }
  __syncthreads();

  const float INVS = 0.022097086912079608f;  // 1/sqrt(2048)
#pragma unroll
  for (int p = 0; p < 64; ++p)
    sc[p] = (red[p] + red[64 + p] + red[128 + p] + red[192 + p]) * INVS;

#pragma unroll
  for (int t = 0; t < 8; ++t) {
    float m = sc[t * 8];
#pragma unroll
    for (int s = 1; s < 8; ++s) m = fmaxf(m, sc[t * 8 + s]);
    float l = 0.f;
#pragma unroll
    for (int s = 0; s < 8; ++s) {
      float e = __expf(sc[t * 8 + s] - m);
      sc[t * 8 + s] = e;
      l += e;
    }
    float inv = 1.f / l;
#pragma unroll
    for (int s = 0; s < 8; ++s) sc[t * 8 + s] *= inv;
  }

  u32 vw[8][4];
#pragma unroll
  for (int s = 0; s < 8; ++s) {
    uint4 v = *reinterpret_cast<const uint4*>(Vb + rbase + s * 2048 + e0);
    vw[s][0] = v.x; vw[s][1] = v.y; vw[s][2] = v.z; vw[s][3] = v.w;
  }

  for (int t = 0; t < 8; ++t) {
    float cx[8];
#pragma unroll
    for (int j = 0; j < 8; ++j) cx[j] = 0.f;
#pragma unroll
    for (int s = 0; s < 8; ++s) {
      float a = sc[t * 8 + s];
#pragma unroll
      for (int c = 0; c < 4; ++c) {
        cx[2 * c]     += a * blo(vw[s][c]);
        cx[2 * c + 1] += a * bhi(vw[s][c]);
      }
    }
    uint4 gu = *reinterpret_cast<const uint4*>(Gb + rbase + t * 2048 + e0);
    uint4 hu = *reinterpret_cast<const uint4*>(Hb + rbase + t * 2048 + e0);
    u32 ga[4] = {gu.x, gu.y, gu.z, gu.w};
    u32 ha[4] = {hu.x, hu.y, hu.z, hu.w};
    float bgv[8];
    *reinterpret_cast<float4*>(&bgv[0]) = *reinterpret_cast<const float4*>(bgp + t * 2048 + e0);
    *reinterpret_cast<float4*>(&bgv[4]) = *reinterpret_cast<const float4*>(bgp + t * 2048 + e0 + 4);
    float x[8];
    float s1 = 0.f, s2 = 0.f;
#pragma unroll
    for (int c = 0; c < 4; ++c) {
      float gl = blo(ga[c]) + bgv[2 * c];
      float gh = bhi(ga[c]) + bgv[2 * c + 1];
      float sgl = 1.f / (1.f + __expf(-gl));
      float sgh = 1.f / (1.f + __expf(-gh));
      float xl = blo(ha[c]) + sgl * cx[2 * c];
      float xh = bhi(ha[c]) + sgh * cx[2 * c + 1];
      x[2 * c] = xl; x[2 * c + 1] = xh;
      s1 += xl + xh;
      s2 += xl * xl + xh * xh;
    }
#pragma unroll
    for (int m = 1; m < 64; m <<= 1) {
      s1 += __shfl_xor(s1, m, 64);
      s2 += __shfl_xor(s2, m, 64);
    }
    if (lane == 0) { r1s[wid] = s1; r2s[wid] = s2; }
    __syncthreads();
    const float invD = 1.f / 2048.f;
    float S1 = r1s[0] + r1s[1] + r1s[2] + r1s[3];
    float S2 = r2s[0] + r2s[1] + r2s[2] + r2s[3];
    float mu = S1 * invD;
    float var = S2 * invD - mu * mu;
    float rstd = rsqrtf(var + 1e-5f);
    float gmv[8], btv[8];
    *reinterpret_cast<float4*>(&gmv[0]) = *reinterpret_cast<const float4*>(gap + t * 2048 + e0);
    *reinterpret_cast<float4*>(&gmv[4]) = *reinterpret_cast<const float4*>(gap + t * 2048 + e0 + 4);
    *reinterpret_cast<float4*>(&btv[0]) = *reinterpret_cast<const float4*>(bep + t * 2048 + e0);
    *reinterpret_cast<float4*>(&btv[4]) = *reinterpret_cast<const float4*>(bep + t * 2048 + e0 + 4);
    float4 o1, o2;
    o1.x = (x[0] - mu) * rstd * gmv[0] + btv[0];
    o1.y = (x[1] - mu) * rstd * gmv[1] + btv[1];
    o1.z = (x[2] - mu) * rstd * gmv[2] + btv[2];
    o1.w = (x[3] - mu) * rstd * gmv[3] + btv[3];
    o2.x = (x[4] - mu) * rstd * gmv[4] + btv[4];
    o2.y = (x[5] - mu) * rstd * gmv[5] + btv[5];
    o2.z = (x[6] - mu) * rstd * gmv[6] + btv[6];
    o2.w = (x[7] - mu) * rstd * gmv[7] + btv[7];
    *reinterpret_cast<float4*>(Out + rbase + t * 2048 + e0) = o1;
    *reinterpret_cast<float4*>(Out + rbase + t * 2048 + e0 + 4) = o2;
    __syncthreads();
  }
}

// ---------------------------------------------------------------------------
extern "C" void kernel_launch(void* const* d_in, const int* in_sizes, int n_in,
                              void* d_out, int out_size, void* d_ws, size_t ws_size,
                              hipStream_t stream)
{
  const float* H  = (const float*)d_in[0];
  const float* Wq = (const float*)d_in[1];
  const float* Wk = (const float*)d_in[2];
  const float* Wv = (const float*)d_in[3];
  const float* Wg = (const float*)d_in[4];
  const float* bg = (const float*)d_in[5];
  const float* ga = (const float*)d_in[6];
  const float* be = (const float*)d_in[7];
  float* Out = (float*)d_out;

  const size_t NWQ = 33554432, NWK = 4194304;
  // ws layout (u16 elems): Wqb | Wgb | Wkb | Wvb | per-chunk {Hb, K, V, G, Q}
  u16* Wqb = (u16*)d_ws;
  u16* Wgb = Wqb + NWQ;
  u16* Wkb = Wgb + NWQ;
  u16* Wvb = Wkb + NWK;
  u16* chunkbase = Wvb + NWK;  // 150,994,944 bytes

  // chunk over batches: per batch needs 5 * 16384 * 2 = 163840 bytes.
  // CB must stay >= 256 (Q/G GEMM uses 128-row tiles; K/V 128-row needs
  // CB*8 % 128 == 0 -> CB >= 16) -> nch <= 16.
  const size_t fixed = 150994944ull;
  int nch = 1;
  while (nch < 16 && fixed + (size_t)(4096 / nch) * 163840ull > ws_size) nch <<= 1;
  const int CB = 4096 / nch;

  u16* Hb = chunkbase;
  u16* Kw = Hb + (size_t)CB * 16384;
  u16* Vw = Kw + (size_t)CB * 16384;
  u16* Gw = Vw + (size_t)CB * 16384;
  u16* Qw = Gw + (size_t)CB * 16384;

  // convert weights once per call
  ctil_cvt_f2b<<<2048, 256, 0, stream>>>(Wq, Wqb, (long)NWQ);
  ctil_cvt_f2b<<<2048, 256, 0, stream>>>(Wg, Wgb, (long)NWQ);
  ctil_cvt_f2b<<<512, 256, 0, stream>>>(Wk, Wkb, (long)NWK);
  ctil_cvt_f2b<<<512, 256, 0, stream>>>(Wv, Wvb, (long)NWK);

  for (int c = 0; c < nch; ++c) {
    const size_t off = (size_t)c * (size_t)CB * 16384;
    // convert H chunk
    ctil_cvt_f2b<<<2048, 256, 0, stream>>>(H + off, Hb, (long)CB * 16384);
    // K, V: M = CB*8 rows -> CB/16 m-tiles of 128
    ctil_gemm128<<<dim3(CB / 16, 8, 2), 512, 0, stream>>>(
        Hb, Wqb, Wkb, Wvb, Wgb, Kw, Vw, Qw, Gw, 0);
    // Q_t, Gpre_t: M = CB rows -> CB/128 m-tiles, 16 slices
    ctil_gemm128<<<dim3(CB / 128, 8, 16), 512, 0, stream>>>(
        Hb, Wqb, Wkb, Wvb, Wgb, Kw, Vw, Qw, Gw, 2);
    // fused attention + gate + residual + LN
    ctil_epilogue<<<dim3(CB), 256, 0, stream>>>(
        Hb, Kw, Vw, Qw, Gw, bg, ga, be, Out + off);
  }
}

// Round 14
// 1575.049 us; speedup vs baseline: 6.6305x; 1.0775x over previous
//
#include <hip/hip_runtime.h>
#include <cstdint>

typedef unsigned short u16;
typedef uint32_t u32;
typedef float f32x4 __attribute__((ext_vector_type(4)));
typedef __bf16 bf16x8 __attribute__((ext_vector_type(8)));

#define GLDS16(gp, lp)                                                                   \
  __builtin_amdgcn_global_load_lds((const __attribute__((address_space(1))) void*)(gp),  \
                                   (__attribute__((address_space(3))) void*)(lp), 16, 0, 0)

__device__ __forceinline__ float blo(u32 u) { return __uint_as_float(u << 16); }
__device__ __forceinline__ float bhi(u32 u) { return __uint_as_float(u & 0xFFFF0000u); }
__device__ __forceinline__ u16 f2b(float f) {
  u32 u = __float_as_uint(f);
  u32 r = u + 0x7FFFu + ((u >> 16) & 1u);
  return (u16)(r >> 16);
}

// ---------------------------------------------------------------------------
// f32 -> bf16 conversion (rte), 8 elements per thread, grid-stride.
// ---------------------------------------------------------------------------
__global__ __launch_bounds__(256) void ctil_cvt_f2b(
    const float* __restrict__ in, u16* __restrict__ out, long n)
{
  long i = ((long)blockIdx.x * blockDim.x + threadIdx.x) * 8;
  const long stride = (long)gridDim.x * blockDim.x * 8;
  for (; i < n; i += stride) {
    float4 a = *reinterpret_cast<const float4*>(in + i);
    float4 b = *reinterpret_cast<const float4*>(in + i + 4);
    uint4 o;
    o.x = (u32)f2b(a.x) | ((u32)f2b(a.y) << 16);
    o.y = (u32)f2b(a.z) | ((u32)f2b(a.w) << 16);
    o.z = (u32)f2b(b.x) | ((u32)f2b(b.y) << 16);
    o.w = (u32)f2b(b.z) | ((u32)f2b(b.w) << 16);
    *reinterpret_cast<uint4*>(out + i) = o;
  }
}

// ---------------------------------------------------------------------------
// Merged f32->bf16 conversion: 5 segments in one launch (all sizes % 8 == 0).
// ---------------------------------------------------------------------------
__global__ __launch_bounds__(256) void ctil_cvt_multi(
    const float* __restrict__ s0, u16* __restrict__ d0, long n0,
    const float* __restrict__ s1, u16* __restrict__ d1, long n1,
    const float* __restrict__ s2, u16* __restrict__ d2, long n2,
    const float* __restrict__ s3, u16* __restrict__ d3, long n3,
    const float* __restrict__ s4, u16* __restrict__ d4, long n4)
{
  const long total = n0 + n1 + n2 + n3 + n4;
  long i = ((long)blockIdx.x * blockDim.x + threadIdx.x) * 8;
  const long stride = (long)gridDim.x * blockDim.x * 8;
  for (; i < total; i += stride) {
    const float* s;
    u16* d;
    long off = i;
    if (off < n0) { s = s0; d = d0; }
    else if ((off -= n0) < n1) { s = s1; d = d1; }
    else if ((off -= n1) < n2) { s = s2; d = d2; }
    else if ((off -= n2) < n3) { s = s3; d = d3; }
    else { off -= n3; s = s4; d = d4; }
    float4 a = *reinterpret_cast<const float4*>(s + off);
    float4 b = *reinterpret_cast<const float4*>(s + off + 4);
    uint4 o;
    o.x = (u32)f2b(a.x) | ((u32)f2b(a.y) << 16);
    o.y = (u32)f2b(a.z) | ((u32)f2b(a.w) << 16);
    o.z = (u32)f2b(b.x) | ((u32)f2b(b.y) << 16);
    o.w = (u32)f2b(b.z) | ((u32)f2b(b.w) << 16);
    *reinterpret_cast<uint4*>(d + off) = o;
  }
}

// ---------------------------------------------------------------------------
// 256x256 8-phase GEMM (r7 fence-light schedule, best verified ~41% MfmaUtil):
// C(M,2048) = A(M,2048) @ W(2048,2048)^T, bf16, f32 acc.
// 8 waves (2M x 4N), per-wave 128x64, BK=64, LDS 2x(A 256x64 + B 256x64).
// T2 st-swizzle on reads; linear global_load_lds dest, inverse-swizzled src.
// HW-required waits only: counted vmcnt(4)+BAR publish at P3/P7; lgkmcnt(0)
// before end-BAR of P2/P6 (cross-wave WAR guard). One barrier per phase.
// MERGED launch: 1-D grid covering KV tiles [0, nKV) then QG tiles.
//   KV: z in {0,1}, m-tiles = CB/32 (M = CB*8), lda/ldc = 2048.
//   QG: z in {2..17}, m-tiles = CB/256 (M = CB), lda/ldc = 16384.
// ---------------------------------------------------------------------------
__global__ __launch_bounds__(512, 2) void ctil_gemm256m(
    const u16* __restrict__ Hb, const u16* __restrict__ Wqb,
    const u16* __restrict__ Wkb, const u16* __restrict__ Wvb,
    const u16* __restrict__ Wgb,
    u16* __restrict__ Kb, u16* __restrict__ Vb,
    u16* __restrict__ Qb, u16* __restrict__ Gb,
    int CB)
{
  // decode merged 1-D grid (all-scalar)
  const int nKVm = CB / 32;          // KV m-tiles per z
  const int nKV = nKVm * 8 * 2;
  int z, bm, bn;
  {
    const int b = (int)blockIdx.x;
    if (b < nKV) {
      bm = b % nKVm;
      bn = (b / nKVm) & 7;
      z = b / (nKVm * 8);
    } else {
      const int b2 = b - nKV;
      const int mt = CB / 256;
      bm = b2 % mt;
      bn = (b2 / mt) & 7;
      z = 2 + b2 / (mt * 8);
    }
  }
  const u16* A;
  const u16* W;
  u16* C;
  int lda, ldc;
  if (z < 2) {
    A = Hb; lda = 2048; ldc = 2048;
    W = (z == 0) ? Wkb : Wvb;
    C = (z == 0) ? Kb : Vb;
  } else {
    const int t = (z - 2) & 7;
    A = Hb + t * 2048; lda = 16384; ldc = 16384;
    W = ((z < 10) ? Wqb : Wgb) + (size_t)t * (size_t)(2048 * 2048);
    C = ((z < 10) ? Qb : Gb) + t * 2048;
  }

  const int tid = (int)threadIdx.x;
  const int lane = tid & 63, wid = tid >> 6;
  const int wm = wid >> 2, wn = wid & 3;   // 2 x 4 wave grid

  __shared__ __align__(16) u16 As[2][16384];   // [buf][row*64 + k]
  __shared__ __align__(16) u16 Bs[2][16384];

  // staging map: issue h covers rows h*64..h*64+63; wave wid stages rows
  // h*64 + wid*8 + (lane>>3); physical slot lane&7 holds logical kslot
  // (lane&7)^(lane>>3)  (inverse of the read swizzle).
  const int srl = lane >> 3;
  const int sq  = (lane & 7) ^ srl;
  const u16* Ag = A + (size_t)(bm * 256 + wid * 8 + srl) * lda + sq * 8;
  const u16* Bg = W + (size_t)(bn * 256 + wid * 8 + srl) * 2048 + sq * 8;

#define STAGE(buf, kt, h)                                                     \
  do {                                                                        \
    GLDS16(Ag + (size_t)((h) * 64) * lda + (kt) * 64,                         \
           &As[buf][((h) * 64 + wid * 8) * 64]);                              \
    GLDS16(Bg + (size_t)((h) * 64) * 2048 + (kt) * 64,                        \
           &Bs[buf][((h) * 64 + wid * 8) * 64]);                              \
  } while (0)

  // fragment read addressing (swizzled): logical kslot q of row r lives at
  // u16 index r*64 + (q ^ (r&7))*8.
  const int la = lane & 15, g = lane >> 4, x = lane & 7;
  const int arow = wm * 128 + la;   // + mh*64 + j*16
  const int brow = wn * 64 + la;    // + nh*32 + j*16
  const int sl0 = (g ^ x) << 3;           // ks=0
  const int sl1 = ((4 | g) ^ x) << 3;     // ks=1

  bf16x8 aR[4][2];        // A frags: current mh, [j][ks]
  bf16x8 bR[2][2][2];     // B frags: both halves live, [nh][jj][ks]
  f32x4 acc[8][4] = {};

#define DSA(buf, mh)                                                          \
  do {                                                                        \
    _Pragma("unroll") for (int j = 0; j < 4; ++j) {                           \
      const int r_ = (arow + (mh) * 64 + j * 16) * 64;                        \
      aR[j][0] = *reinterpret_cast<const bf16x8*>(&As[buf][r_ + sl0]);        \
      aR[j][1] = *reinterpret_cast<const bf16x8*>(&As[buf][r_ + sl1]);        \
    }                                                                         \
  } while (0)

#define DSB(buf, nh)                                                          \
  do {                                                                        \
    _Pragma("unroll") for (int j = 0; j < 2; ++j) {                           \
      const int r_ = (brow + (nh) * 32 + j * 16) * 64;                        \
      bR[nh][j][0] = *reinterpret_cast<const bf16x8*>(&Bs[buf][r_ + sl0]);    \
      bR[nh][j][1] = *reinterpret_cast<const bf16x8*>(&Bs[buf][r_ + sl1]);    \
    }                                                                         \
  } while (0)

#define MFMA16(mh, nh)                                                        \
  do {                                                                        \
    _Pragma("unroll") for (int j = 0; j < 4; ++j)                             \
    _Pragma("unroll") for (int jj = 0; jj < 2; ++jj)                          \
    _Pragma("unroll") for (int ks = 0; ks < 2; ++ks)                          \
      acc[(mh) * 4 + j][(nh) * 2 + jj] =                                      \
          __builtin_amdgcn_mfma_f32_16x16x32_bf16(                            \
              aR[j][ks], bR[nh][jj][ks], acc[(mh) * 4 + j][(nh) * 2 + jj],    \
              0, 0, 0);                                                       \
  } while (0)

#define BAR()                                                                 \
  do {                                                                        \
    __builtin_amdgcn_s_barrier();                                             \
    asm volatile("" ::: "memory");                                            \
  } while (0)
#define LGKMW() asm volatile("s_waitcnt lgkmcnt(0)" ::: "memory")
#define VMW(n) asm volatile("s_waitcnt vmcnt(" #n ")" ::: "memory")
#define PRIO_ON()  __builtin_amdgcn_s_setprio(1)
#define PRIO_OFF() __builtin_amdgcn_s_setprio(0)

  // prologue: buf0 <- tile0 (8 loads); buf1 <- tile1 h0,h1 (4 loads);
  // publish buf0: vmcnt(4) + BAR.
#pragma unroll
  for (int h = 0; h < 4; ++h) STAGE(0, 0, h);
  STAGE(1, 1, 0);
  STAGE(1, 1, 1);
  VMW(4);
  BAR();

#pragma unroll 1
  for (int it = 0; it < 16; ++it) {
    const int k1 = 2 * it + 1, k2 = 2 * it + 2, k3 = 2 * it + 3;
    const bool nl = (it < 15);
    // ---- P0: reads of buf0 quadrant (0,0); finish buf1(k1) staging.
    DSA(0, 0); DSB(0, 0);
    STAGE(1, k1, 2);
    STAGE(1, k1, 3);
    PRIO_ON(); MFMA16(0, 0); PRIO_OFF();
    BAR();
    // ---- P1
    DSB(0, 1);
    PRIO_ON(); MFMA16(0, 1); PRIO_OFF();
    BAR();
    // ---- P2 (last buf0 reads; WAR guard before buf0 overwrite at P3)
    DSA(0, 1);
    PRIO_ON(); MFMA16(1, 1); PRIO_OFF();
    LGKMW();
    BAR();
    // ---- P3: stage buf0(k2) h0,h1; publish buf1(k1): vmcnt(4)+BAR.
    if (nl) { STAGE(0, k2, 0); STAGE(0, k2, 1); }
    PRIO_ON(); MFMA16(1, 0); PRIO_OFF();
    if (nl) VMW(4); else VMW(0);
    BAR();
    // ---- P4: reads of buf1 quadrant (0,0); finish buf0(k2) staging.
    DSA(1, 0); DSB(1, 0);
    if (nl) { STAGE(0, k2, 2); STAGE(0, k2, 3); }
    PRIO_ON(); MFMA16(0, 0); PRIO_OFF();
    BAR();
    // ---- P5
    DSB(1, 1);
    PRIO_ON(); MFMA16(0, 1); PRIO_OFF();
    BAR();
    // ---- P6 (last buf1 reads; WAR guard before buf1 overwrite at P7)
    DSA(1, 1);
    PRIO_ON(); MFMA16(1, 1); PRIO_OFF();
    LGKMW();
    BAR();
    // ---- P7: stage buf1(k3) h0,h1; publish buf0(k2): vmcnt(4)+BAR.
    if (nl) { STAGE(1, k3, 0); STAGE(1, k3, 1); }
    PRIO_ON(); MFMA16(1, 0); PRIO_OFF();
    if (nl) VMW(4); else VMW(0);
    BAR();
  }

  // ---- epilogue: C write (C/D layout: col=lane&15, row=(lane>>4)*4+r)
  const int cl = lane & 15, cq = lane >> 4;
#pragma unroll
  for (int mf = 0; mf < 8; ++mf) {
#pragma unroll
    for (int r = 0; r < 4; ++r) {
      const int row = bm * 256 + wm * 128 + mf * 16 + cq * 4 + r;
      u16* Cr = C + (size_t)row * ldc + bn * 256 + wn * 64 + cl;
#pragma unroll
      for (int nf = 0; nf < 4; ++nf)
        Cr[nf * 16] = f2b(acc[mf][nf][r]);
    }
  }
#undef STAGE
#undef DSA
#undef DSB
#undef MFMA16
#undef BAR
#undef LGKMW
#undef VMW
}

// ---------------------------------------------------------------------------
// Fused epilogue: per batch b (one 256-thread block):
//   scores = Q K^T / sqrt(D) -> softmax -> ctx = attn V
//   g = sigmoid(Gpre + bg); x = H + g*ctx; out = LayerNorm(x)*gamma + beta
// Each thread owns an 8-wide contiguous e-slice (e0 = tid*8).
// Hb/K/V/Q/G are bf16; bg/gamma/beta are f32; Out is f32.
// ---------------------------------------------------------------------------
__global__ __launch_bounds__(256) void ctil_epilogue(
    const u16* __restrict__ Hb, const u16* __restrict__ Kb,
    const u16* __restrict__ Vb, const u16* __restrict__ Qb,
    const u16* __restrict__ Gb, const float* __restrict__ bgp,
    const float* __restrict__ gap, const float* __restrict__ bep,
    float* __restrict__ Out)
{
  const int b = blockIdx.x;
  const int tid = (int)threadIdx.x;
  const int lane = tid & 63, wid = tid >> 6;
  const size_t rbase = (size_t)b * 16384;
  const int e0 = tid * 8;

  __shared__ float red[256];
  __shared__ float r1s[4], r2s[4];

  u32 qw[8][4], kw[8][4];
#pragma unroll
  for (int t = 0; t < 8; ++t) {
    uint4 v = *reinterpret_cast<const uint4*>(Qb + rbase + t * 2048 + e0);
    qw[t][0] = v.x; qw[t][1] = v.y; qw[t][2] = v.z; qw[t][3] = v.w;
    uint4 w = *reinterpret_cast<const uint4*>(Kb + rbase + t * 2048 + e0);
    kw[t][0] = w.x; kw[t][1] = w.y; kw[t][2] = w.z; kw[t][3] = w.w;
  }

  float sc[64];
#pragma unroll
  for (int p = 0; p < 64; ++p) sc[p] = 0.f;

#pragma unroll
  for (int c = 0; c < 4; ++c) {
    float ql[8], qh[8], kl[8], kh[8];
#pragma unroll
    for (int t = 0; t < 8; ++t) {
      ql[t] = blo(qw[t][c]); qh[t] = bhi(qw[t][c]);
      kl[t] = blo(kw[t][c]); kh[t] = bhi(kw[t][c]);
    }
#pragma unroll
    for (int t = 0; t < 8; ++t)
#pragma unroll
      for (int s = 0; s < 8; ++s)
        sc[t * 8 + s] += ql[t] * kl[s] + qh[t] * kh[s];
  }

#pragma unroll
  for (int p = 0; p < 64; ++p) {
    float v = sc[p];
#pragma unroll
    for (int m = 1; m < 64; m <<= 1) v += __shfl_xor(v, m, 64);
    sc[p] = v;
  }
  if (lane == 0) {
#pragma unroll
    for (int p = 0; p < 64; ++p) red[wid * 64 + p] = sc[p];
  }
  __syncthreads();

  const float INVS = 0.022097086912079608f;  // 1/sqrt(2048)
#pragma unroll
  for (int p = 0; p < 64; ++p)
    sc[p] = (red[p] + red[64 + p] + red[128 + p] + red[192 + p]) * INVS;

#pragma unroll
  for (int t = 0; t < 8; ++t) {
    float m = sc[t * 8];
#pragma unroll
    for (int s = 1; s < 8; ++s) m = fmaxf(m, sc[t * 8 + s]);
    float l = 0.f;
#pragma unroll
    for (int s = 0; s < 8; ++s) {
      float e = __expf(sc[t * 8 + s] - m);
      sc[t * 8 + s] = e;
      l += e;
    }
    float inv = 1.f / l;
#pragma unroll
    for (int s = 0; s < 8; ++s) sc[t * 8 + s] *= inv;
  }

  u32 vw[8][4];
#pragma unroll
  for (int s = 0; s < 8; ++s) {
    uint4 v = *reinterpret_cast<const uint4*>(Vb + rbase + s * 2048 + e0);
    vw[s][0] = v.x; vw[s][1] = v.y; vw[s][2] = v.z; vw[s][3] = v.w;
  }

  for (int t = 0; t < 8; ++t) {
    float cx[8];
#pragma unroll
    for (int j = 0; j < 8; ++j) cx[j] = 0.f;
#pragma unroll
    for (int s = 0; s < 8; ++s) {
      float a = sc[t * 8 + s];
#pragma unroll
      for (int c = 0; c < 4; ++c) {
        cx[2 * c]     += a * blo(vw[s][c]);
        cx[2 * c + 1] += a * bhi(vw[s][c]);
      }
    }
    uint4 gu = *reinterpret_cast<const uint4*>(Gb + rbase + t * 2048 + e0);
    uint4 hu = *reinterpret_cast<const uint4*>(Hb + rbase + t * 2048 + e0);
    u32 ga[4] = {gu.x, gu.y, gu.z, gu.w};
    u32 ha[4] = {hu.x, hu.y, hu.z, hu.w};
    float bgv[8];
    *reinterpret_cast<float4*>(&bgv[0]) = *reinterpret_cast<const float4*>(bgp + t * 2048 + e0);
    *reinterpret_cast<float4*>(&bgv[4]) = *reinterpret_cast<const float4*>(bgp + t * 2048 + e0 + 4);
    float x[8];
    float s1 = 0.f, s2 = 0.f;
#pragma unroll
    for (int c = 0; c < 4; ++c) {
      float gl = blo(ga[c]) + bgv[2 * c];
      float gh = bhi(ga[c]) + bgv[2 * c + 1];
      float sgl = 1.f / (1.f + __expf(-gl));
      float sgh = 1.f / (1.f + __expf(-gh));
      float xl = blo(ha[c]) + sgl * cx[2 * c];
      float xh = bhi(ha[c]) + sgh * cx[2 * c + 1];
      x[2 * c] = xl; x[2 * c + 1] = xh;
      s1 += xl + xh;
      s2 += xl * xl + xh * xh;
    }
#pragma unroll
    for (int m = 1; m < 64; m <<= 1) {
      s1 += __shfl_xor(s1, m, 64);
      s2 += __shfl_xor(s2, m, 64);
    }
    if (lane == 0) { r1s[wid] = s1; r2s[wid] = s2; }
    __syncthreads();
    const float invD = 1.f / 2048.f;
    float S1 = r1s[0] + r1s[1] + r1s[2] + r1s[3];
    float S2 = r2s[0] + r2s[1] + r2s[2] + r2s[3];
    float mu = S1 * invD;
    float var = S2 * invD - mu * mu;
    float rstd = rsqrtf(var + 1e-5f);
    float gmv[8], btv[8];
    *reinterpret_cast<float4*>(&gmv[0]) = *reinterpret_cast<const float4*>(gap + t * 2048 + e0);
    *reinterpret_cast<float4*>(&gmv[4]) = *reinterpret_cast<const float4*>(gap + t * 2048 + e0 + 4);
    *reinterpret_cast<float4*>(&btv[0]) = *reinterpret_cast<const float4*>(bep + t * 2048 + e0);
    *reinterpret_cast<float4*>(&btv[4]) = *reinterpret_cast<const float4*>(bep + t * 2048 + e0 + 4);
    float4 o1, o2;
    o1.x = (x[0] - mu) * rstd * gmv[0] + btv[0];
    o1.y = (x[1] - mu) * rstd * gmv[1] + btv[1];
    o1.z = (x[2] - mu) * rstd * gmv[2] + btv[2];
    o1.w = (x[3] - mu) * rstd * gmv[3] + btv[3];
    o2.x = (x[4] - mu) * rstd * gmv[4] + btv[4];
    o2.y = (x[5] - mu) * rstd * gmv[5] + btv[5];
    o2.z = (x[6] - mu) * rstd * gmv[6] + btv[6];
    o2.w = (x[7] - mu) * rstd * gmv[7] + btv[7];
    *reinterpret_cast<float4*>(Out + rbase + t * 2048 + e0) = o1;
    *reinterpret_cast<float4*>(Out + rbase + t * 2048 + e0 + 4) = o2;
    __syncthreads();
  }
}

// ---------------------------------------------------------------------------
extern "C" void kernel_launch(void* const* d_in, const int* in_sizes, int n_in,
                              void* d_out, int out_size, void* d_ws, size_t ws_size,
                              hipStream_t stream)
{
  const float* H  = (const float*)d_in[0];
  const float* Wq = (const float*)d_in[1];
  const float* Wk = (const float*)d_in[2];
  const float* Wv = (const float*)d_in[3];
  const float* Wg = (const float*)d_in[4];
  const float* bg = (const float*)d_in[5];
  const float* ga = (const float*)d_in[6];
  const float* be = (const float*)d_in[7];
  float* Out = (float*)d_out;

  const size_t NWQ = 33554432, NWK = 4194304;
  // ws layout (u16 elems): Wqb | Wgb | Wkb | Wvb | per-chunk {Hb, K, V, G, Q}
  u16* Wqb = (u16*)d_ws;
  u16* Wgb = Wqb + NWQ;
  u16* Wkb = Wgb + NWQ;
  u16* Wvb = Wkb + NWK;
  u16* chunkbase = Wvb + NWK;  // 150,994,944 bytes

  // chunk over batches: per batch needs 5 * 16384 * 2 = 163840 bytes.
  // CB must stay >= 256 (Q/G GEMM uses 256-row tiles) -> nch <= 16.
  const size_t fixed = 150994944ull;
  int nch = 1;
  while (nch < 16 && fixed + (size_t)(4096 / nch) * 163840ull > ws_size) nch <<= 1;
  const int CB = 4096 / nch;

  u16* Hb = chunkbase;
  u16* Kw = Hb + (size_t)CB * 16384;
  u16* Vw = Kw + (size_t)CB * 16384;
  u16* Gw = Vw + (size_t)CB * 16384;
  u16* Qw = Gw + (size_t)CB * 16384;

  const int nTiles = (CB / 32) * 16 + (CB / 256) * 128;  // KV + QG tiles

  for (int c = 0; c < nch; ++c) {
    const size_t off = (size_t)c * (size_t)CB * 16384;
    if (c == 0) {
      // one merged conversion: 4 weights + first H chunk
      ctil_cvt_multi<<<4096, 256, 0, stream>>>(
          Wq, Wqb, (long)NWQ, Wg, Wgb, (long)NWQ,
          Wk, Wkb, (long)NWK, Wv, Wvb, (long)NWK,
          H, Hb, (long)CB * 16384);
    } else {
      ctil_cvt_f2b<<<2048, 256, 0, stream>>>(H + off, Hb, (long)CB * 16384);
    }
    // merged GEMM launch: K, V, Q_t, Gpre_t in one dispatch
    ctil_gemm256m<<<dim3(nTiles), 512, 0, stream>>>(
        Hb, Wqb, Wkb, Wvb, Wgb, Kw, Vw, Qw, Gw, CB);
    // fused attention + gate + residual + LN
    ctil_epilogue<<<dim3(CB), 256, 0, stream>>>(
        Hb, Kw, Vw, Qw, Gw, bg, ga, be, Out + off);
  }
}